// Round 8
// baseline (242.430 us; speedup 1.0000x reference)
//
#include <hip/hip_runtime.h>
#include <hip/hip_bf16.h>

#define DIM 2048
#define S_LEN 2048
#define N_HEADS 32
#define N_KV_HEADS 8
#define HEAD_DIM 64
#define KV_DIM (N_KV_HEADS * HEAD_DIM)   // 512
#define QKV_N (DIM + 2 * KV_DIM)         // 3072
#define QSCALE 0.18033688011112042f      // 0.125 * log2(e), folded into Q at rope

typedef __attribute__((ext_vector_type(8))) short bf16x8;
typedef __attribute__((ext_vector_type(4))) float f32x4;

__device__ __forceinline__ unsigned short bf16_of(float f) {
    __hip_bfloat16 h = __float2bfloat16(f);
    return *reinterpret_cast<unsigned short*>(&h);
}
__device__ __forceinline__ float f_of_bf16(unsigned short u) {
    unsigned int x = ((unsigned int)u) << 16;
    return __uint_as_float(x);
}
__device__ __forceinline__ void gl_lds16(const void* g, void* l) {
    __builtin_amdgcn_global_load_lds((const __attribute__((address_space(1))) void*)g,
                                     (__attribute__((address_space(3))) void*)l, 16, 0, 0);
}
// pack two fp32 -> bf16x2 by truncation: one v_perm_b32
__device__ __forceinline__ unsigned int pack2tr(float lo, float hi) {
    return __builtin_amdgcn_perm(__float_as_uint(hi), __float_as_uint(lo), 0x07060302u);
}

// ---------------------------------------------------------------------------
// prep: fused x->bf16 convert (blocks 0..4095) + 4 weight transpose/converts
// (blocks 4096..6655).  All weight transposes land in [N][K=2048] bf16.
// ---------------------------------------------------------------------------
__global__ __launch_bounds__(256) void prep(const float* __restrict__ x,
                                            const float* __restrict__ wq,
                                            const float* __restrict__ wk,
                                            const float* __restrict__ wv,
                                            const float* __restrict__ wo,
                                            unsigned short* __restrict__ xbf,
                                            unsigned short* __restrict__ wqkvT,
                                            unsigned short* __restrict__ woT) {
    __shared__ float tile[64][65];
    const int t = threadIdx.x;
    int b = blockIdx.x;
    if (b < 4096) {
        int idx = b * 256 + t;
        float4 f = ((const float4*)x)[idx];
        ushort4 u;
        u.x = bf16_of(f.x); u.y = bf16_of(f.y); u.z = bf16_of(f.z); u.w = bf16_of(f.w);
        ((ushort4*)xbf)[idx] = u;
        return;
    }
    b -= 4096;
    const float* src;
    unsigned short* dst;
    int src_cols, bx, by;
    if (b < 1024)      { src = wq; dst = wqkvT;                                src_cols = DIM;    bx = b & 31;          by = b >> 5; }
    else if (b < 1280) { src = wk; dst = wqkvT + (size_t)DIM * DIM;            src_cols = KV_DIM; bx = (b - 1024) & 7;  by = (b - 1024) >> 3; }
    else if (b < 1536) { src = wv; dst = wqkvT + (size_t)(DIM + KV_DIM) * DIM; src_cols = KV_DIM; bx = (b - 1280) & 7;  by = (b - 1280) >> 3; }
    else               { src = wo; dst = woT;                                  src_cols = DIM;    bx = (b - 1536) & 31; by = (b - 1536) >> 5; }
    const int c0 = bx * 64, r0 = by * 64;
#pragma unroll
    for (int i = 0; i < 16; i++) {
        int idx = t + i * 256;
        int r = idx >> 6, c = idx & 63;
        tile[r][c] = src[(size_t)(r0 + r) * src_cols + c0 + c];
    }
    __syncthreads();
#pragma unroll
    for (int i = 0; i < 16; i++) {
        int idx = t + i * 256;
        int r = idx >> 6, c = idx & 63;
        dst[(size_t)(c0 + r) * DIM + r0 + c] = bf16_of(tile[c][r]);
    }
}

// ---------------------------------------------------------------------------
// bf16 MFMA GEMM, 128(M) x 64(N) tile, BK=64, 4 waves (2x2, each 64x32).
// C[M][N] = A[M][K] @ Bt[N][K]^T.
// ---------------------------------------------------------------------------
__global__ __launch_bounds__(256) void gemm_bt64(const unsigned short* __restrict__ A,
                                                 const unsigned short* __restrict__ Bt,
                                                 void* __restrict__ Cv,
                                                 int M, int N, int K, int c_bf16) {
    __shared__ unsigned short As[128 * 64];
    __shared__ unsigned short Bs[64 * 64];
    const int tid = threadIdx.x;
    const int wave = tid >> 6, lane = tid & 63;
    const int m16 = lane & 15, quad = lane >> 4;
    const int m0 = blockIdx.y * 128, n0 = blockIdx.x * 64;
    const int wm = (wave >> 1) * 64, wn = (wave & 1) * 32;

    const int lrow = lane >> 3;
    const int gc = (lane & 7) ^ lrow;
    const unsigned short* Ab = A + (size_t)(m0 + wave * 8 + lrow) * K + gc * 8;
    const unsigned short* Bb = Bt + (size_t)(n0 + wave * 8 + lrow) * K + gc * 8;

    f32x4 acc[4][2];
#pragma unroll
    for (int mb = 0; mb < 4; mb++)
#pragma unroll
        for (int nb = 0; nb < 2; nb++) acc[mb][nb] = (f32x4){0.f, 0.f, 0.f, 0.f};

    for (int k0 = 0; k0 < K; k0 += 64) {
#pragma unroll
        for (int g = 0; g < 4; g++)
            gl_lds16(Ab + (size_t)g * 32 * K + k0, &As[(g * 32 + wave * 8) * 64]);
#pragma unroll
        for (int g = 0; g < 2; g++)
            gl_lds16(Bb + (size_t)g * 32 * K + k0, &Bs[(g * 32 + wave * 8) * 64]);
        __syncthreads();
#pragma unroll
        for (int ks = 0; ks < 2; ks++) {
            const int ch = (ks * 4 + quad) ^ (m16 & 7);
            bf16x8 af[4], bfr[2];
#pragma unroll
            for (int mb = 0; mb < 4; mb++)
                af[mb] = *(const bf16x8*)&As[(wm + mb * 16 + m16) * 64 + ch * 8];
#pragma unroll
            for (int nb = 0; nb < 2; nb++)
                bfr[nb] = *(const bf16x8*)&Bs[(wn + nb * 16 + m16) * 64 + ch * 8];
#pragma unroll
            for (int mb = 0; mb < 4; mb++)
#pragma unroll
                for (int nb = 0; nb < 2; nb++)
                    acc[mb][nb] = __builtin_amdgcn_mfma_f32_16x16x32_bf16(af[mb], bfr[nb], acc[mb][nb], 0, 0, 0);
        }
        __syncthreads();
    }

    if (c_bf16) {
        unsigned short* C = (unsigned short*)Cv;
#pragma unroll
        for (int mb = 0; mb < 4; mb++)
#pragma unroll
            for (int nb = 0; nb < 2; nb++)
#pragma unroll
                for (int r = 0; r < 4; r++)
                    C[(size_t)(m0 + wm + mb * 16 + quad * 4 + r) * N + n0 + wn + nb * 16 + m16] =
                        bf16_of(acc[mb][nb][r]);
    } else {
        float* C = (float*)Cv;
#pragma unroll
        for (int mb = 0; mb < 4; mb++)
#pragma unroll
            for (int nb = 0; nb < 2; nb++)
#pragma unroll
                for (int r = 0; r < 4; r++)
                    C[(size_t)(m0 + wm + mb * 16 + quad * 4 + r) * N + n0 + wn + nb * 16 + m16] =
                        acc[mb][nb][r];
    }
}

// ---------------------------------------------------------------------------
// rope_tv: fused RoPE (blocks 0..2559) + V transpose-with-key-permute
// (blocks 2560..2815).  Q pre-scaled by 0.125*log2(e) (exp2 domain).
// V perm within each 128-key block matches the attention PV A-frag order.
// ---------------------------------------------------------------------------
__global__ __launch_bounds__(256) void rope_tv(const unsigned short* __restrict__ qkv,
                                               unsigned short* __restrict__ qbf,
                                               unsigned short* __restrict__ kbf,
                                               unsigned short* __restrict__ vbt,
                                               const float* __restrict__ fcos,
                                               const float* __restrict__ fsin) {
    __shared__ unsigned short tile[64][65];
    const int t = threadIdx.x;
    int b = blockIdx.x;
    if (b < 2560) {
        int idx = b * 256 + t;
        const int nq = S_LEN * N_HEADS * 8;
        int s, j, srcoff, dstoff;
        unsigned short* dst;
        float osc;
        if (idx < nq) {
            s = idx >> 8;
            int rem = idx & 255;
            int h = rem >> 3;
            j = rem & 7;
            srcoff = s * QKV_N + h * 64 + j * 8;
            dstoff = s * DIM + h * 64 + j * 8;
            dst = qbf;
            osc = QSCALE;
        } else {
            int t2 = idx - nq;
            s = t2 >> 6;
            int rem = t2 & 63;
            int h = rem >> 3;
            j = rem & 7;
            srcoff = s * QKV_N + DIM + h * 64 + j * 8;
            dstoff = s * KV_DIM + h * 64 + j * 8;
            dst = kbf;
            osc = 1.0f;
        }
        bf16x8 v8 = *(const bf16x8*)&qkv[srcoff];
        float4 c4 = *(const float4*)&fcos[s * 32 + j * 4];
        float4 s4 = *(const float4*)&fsin[s * 32 + j * 4];
        float cs[4] = {c4.x, c4.y, c4.z, c4.w};
        float sn[4] = {s4.x, s4.y, s4.z, s4.w};
        bf16x8 o;
#pragma unroll
        for (int p = 0; p < 4; p++) {
            float a = f_of_bf16((unsigned short)v8[2 * p]);
            float bb = f_of_bf16((unsigned short)v8[2 * p + 1]);
            o[2 * p]     = (short)bf16_of((a * cs[p] - bb * sn[p]) * osc);
            o[2 * p + 1] = (short)bf16_of((a * sn[p] + bb * cs[p]) * osc);
        }
        *(bf16x8*)&dst[dstoff] = o;
        return;
    }
    b -= 2560;                                    // 0..255  (8 x 32)
    const int d0 = (b & 7) * 64;
    const int s0 = (b >> 3) * 64;
#pragma unroll
    for (int i = 0; i < 16; i++) {
        int idx = t + i * 256;
        int r = idx >> 6, c = idx & 63;
        tile[r][c] = qkv[(size_t)(s0 + r) * QKV_N + DIM + KV_DIM + d0 + c];
    }
    __syncthreads();
#pragma unroll
    for (int i = 0; i < 16; i++) {
        int idx = t + i * 256;
        int r = idx >> 6, c = idx & 63;
        int key = s0 + c;
        int kl = key & 127;
        int kp = (kl & 0x60) | ((kl & 0x0C) << 1) | ((kl & 0x10) >> 2) | (kl & 3);
        vbt[(size_t)(d0 + r) * S_LEN + (key & ~127) + kp] = tile[c][r];
    }
}

// ---------------------------------------------------------------------------
// Flash attention v6: LDS-traffic-centric redesign (R6 showed attn is
// LDS-read-BW bound: K/V frags are wave-invariant, so 4 waves re-read the
// same bytes).  Each wave now carries TWO 16-row Q groups -> every K/V
// ds_read_b128 feeds 2 MFMAs; block covers 128 q-rows; total LDS reads and
// DMA traffic per q-row halve.  Grid 16x32, big tiles first (LPT packing),
// 2 blocks/CU at 64KB dbuf.  Double-buffered DMA, one barrier/iter,
// l-via-MFMA-ones, inline v_perm P packing, exp2-domain softmax.
// ---------------------------------------------------------------------------
__global__ __launch_bounds__(256) void attn_mfma6(const unsigned short* __restrict__ qb,
                                                  const unsigned short* __restrict__ kb,
                                                  const unsigned short* __restrict__ vbt,
                                                  unsigned short* __restrict__ out) {
    const int h  = blockIdx.y;
    const int qt = 15 - blockIdx.x;               // big q-tiles dispatch first
    const int q0 = qt * 128;
    const int n_iter = qt + 1;
    const int kh = h >> 2;
    const int tid  = threadIdx.x;
    const int wave = tid >> 6;
    const int lane = tid & 63;
    const int m16  = lane & 15;
    const int quad = lane >> 4;

    __shared__ unsigned short Ks[2][128 * 64];    // [key][dim], chunk-swizzled
    __shared__ unsigned short Vt[2][64 * 128];    // [dim][key(perm)], chunk-swizzled

    const int lrow8 = lane >> 3;
    const int kc    = (lane & 7) ^ lrow8;
    const int lrow4 = lane >> 4;
    const int vc    = (lane & 15) ^ ((wave * 4 + lrow4) & 7);

    const unsigned short* Kbase = kb + (size_t)kh * 64 + (size_t)(wave * 8 + lrow8) * KV_DIM + kc * 8;
    const unsigned short* Vbase = vbt + (size_t)(kh * 64 + wave * 4 + lrow4) * S_LEN + vc * 8;

    bf16x8 ones;
#pragma unroll
    for (int i = 0; i < 8; i++) ones[i] = (short)0x3F80;   // 1.0 bf16

    // Q fragments for the two 16-row groups (B-operand: n=qrow=m16, k=quad*8+j)
    const int rowA = q0 + wave * 16 + m16;
    const int rowB = rowA + 64;
    bf16x8 qaA[2], qaB[2];
#pragma unroll
    for (int ks = 0; ks < 2; ks++) {
        qaA[ks] = *(const bf16x8*)&qb[(size_t)rowA * DIM + h * 64 + ks * 32 + quad * 8];
        qaB[ks] = *(const bf16x8*)&qb[(size_t)rowB * DIM + h * 64 + ks * 32 + quad * 8];
    }

    f32x4 oA[4], oB[4];
#pragma unroll
    for (int nb = 0; nb < 4; nb++) {
        oA[nb] = (f32x4){0.f, 0.f, 0.f, 0.f};
        oB[nb] = (f32x4){0.f, 0.f, 0.f, 0.f};
    }
    f32x4 lA = (f32x4){0.f, 0.f, 0.f, 0.f};
    f32x4 lB = (f32x4){0.f, 0.f, 0.f, 0.f};
    float mA = -1e30f, mB = -1e30f;

    // prologue: stage tile 0 into buffer 0
#pragma unroll
    for (int g = 0; g < 4; g++) {
        gl_lds16(Kbase + (size_t)(g * 32) * KV_DIM, &Ks[0][(g * 32 + wave * 8) * 64]);
        gl_lds16(Vbase + (size_t)g * 16 * S_LEN, &Vt[0][(g * 16 + wave * 4) * 128]);
    }

    for (int kt = 0; kt < n_iter; kt++) {
        __syncthreads();                           // buf[kt&1] drained; old reads done
        if (kt + 1 < n_iter) {
            const int nb2 = (kt + 1) & 1;
#pragma unroll
            for (int g = 0; g < 4; g++) {
                gl_lds16(Kbase + (size_t)((kt + 1) * 128 + g * 32) * KV_DIM,
                         &Ks[nb2][(g * 32 + wave * 8) * 64]);
                gl_lds16(Vbase + (size_t)g * 16 * S_LEN + (kt + 1) * 128,
                         &Vt[nb2][(g * 16 + wave * 4) * 128]);
            }
        }
        const unsigned short* K_ = Ks[kt & 1];
        const unsigned short* V_ = Vt[kt & 1];

        // ---- S^T = K Q^T for both row groups (K frag read once, used twice) ----
        f32x4 sa[8], sb[8];
#pragma unroll
        for (int cb = 0; cb < 8; cb++) {
            sa[cb] = (f32x4){0.f, 0.f, 0.f, 0.f};
            sb[cb] = (f32x4){0.f, 0.f, 0.f, 0.f};
        }
#pragma unroll
        for (int ks = 0; ks < 2; ks++) {
            const int slot = (ks * 4 + quad) ^ (m16 & 7);
#pragma unroll
            for (int cb = 0; cb < 8; cb++) {
                bf16x8 kf = *(const bf16x8*)&K_[(cb * 16 + m16) * 64 + slot * 8];
                sa[cb] = __builtin_amdgcn_mfma_f32_16x16x32_bf16(kf, qaA[ks], sa[cb], 0, 0, 0);
                sb[cb] = __builtin_amdgcn_mfma_f32_16x16x32_bf16(kf, qaB[ks], sb[cb], 0, 0, 0);
            }
        }

        // ---- causal mask (last tile only) ----
        if (kt == n_iter - 1) {
#pragma unroll
            for (int cb = 0; cb < 8; cb++) {
                int key = kt * 128 + cb * 16 + quad * 4;
#pragma unroll
                for (int r = 0; r < 4; r++) {
                    if (key + r > rowA) sa[cb][r] = -1e30f;
                    if (key + r > rowB) sb[cb][r] = -1e30f;
                }
            }
        }

        // ---- online softmax (exp2 domain), both groups ----
        float rmaxA = fmaxf(fmaxf(sa[0][0], sa[0][1]), fmaxf(sa[0][2], sa[0][3]));
        float rmaxB = fmaxf(fmaxf(sb[0][0], sb[0][1]), fmaxf(sb[0][2], sb[0][3]));
#pragma unroll
        for (int cb = 1; cb < 8; cb++) {
            rmaxA = fmaxf(rmaxA, fmaxf(fmaxf(sa[cb][0], sa[cb][1]), fmaxf(sa[cb][2], sa[cb][3])));
            rmaxB = fmaxf(rmaxB, fmaxf(fmaxf(sb[cb][0], sb[cb][1]), fmaxf(sb[cb][2], sb[cb][3])));
        }
        rmaxA = fmaxf(rmaxA, __shfl_xor(rmaxA, 16, 64));
        rmaxB = fmaxf(rmaxB, __shfl_xor(rmaxB, 16, 64));
        rmaxA = fmaxf(rmaxA, __shfl_xor(rmaxA, 32, 64));
        rmaxB = fmaxf(rmaxB, __shfl_xor(rmaxB, 32, 64));

        float mnA = fmaxf(mA, rmaxA);
        float mnB = fmaxf(mB, rmaxB);
        float alA = __builtin_amdgcn_exp2f(mA - mnA);
        float alB = __builtin_amdgcn_exp2f(mB - mnB);
        mA = mnA; mB = mnB;

#pragma unroll
        for (int cb = 0; cb < 8; cb++)
#pragma unroll
            for (int r = 0; r < 4; r++) {
                sa[cb][r] = __builtin_amdgcn_exp2f(sa[cb][r] - mnA);
                sb[cb][r] = __builtin_amdgcn_exp2f(sb[cb][r] - mnB);
            }

        // ---- rescale O and l by alpha of row quad*4+r ----
#pragma unroll
        for (int r = 0; r < 4; r++) {
            float aAr = __shfl(alA, quad * 4 + r, 64);
            float aBr = __shfl(alB, quad * 4 + r, 64);
#pragma unroll
            for (int nb = 0; nb < 4; nb++) { oA[nb][r] *= aAr; oB[nb][r] *= aBr; }
            lA[r] *= aAr; lB[r] *= aBr;
        }

        // ---- O += P V (V frag read once, used twice); l += P @ ones ----
#pragma unroll
        for (int ks = 0; ks < 4; ks++) {
            union { unsigned int u[4]; bf16x8 v; } pA, pB;
            pA.u[0] = pack2tr(sa[2 * ks][0], sa[2 * ks][1]);
            pA.u[1] = pack2tr(sa[2 * ks][2], sa[2 * ks][3]);
            pA.u[2] = pack2tr(sa[2 * ks + 1][0], sa[2 * ks + 1][1]);
            pA.u[3] = pack2tr(sa[2 * ks + 1][2], sa[2 * ks + 1][3]);
            pB.u[0] = pack2tr(sb[2 * ks][0], sb[2 * ks][1]);
            pB.u[1] = pack2tr(sb[2 * ks][2], sb[2 * ks][3]);
            pB.u[2] = pack2tr(sb[2 * ks + 1][0], sb[2 * ks + 1][1]);
            pB.u[3] = pack2tr(sb[2 * ks + 1][2], sb[2 * ks + 1][3]);
            const int slot = (ks * 4 + quad) ^ (m16 & 7);
#pragma unroll
            for (int nb = 0; nb < 4; nb++) {
                bf16x8 vf = *(const bf16x8*)&V_[(nb * 16 + m16) * 128 + slot * 8];
                oA[nb] = __builtin_amdgcn_mfma_f32_16x16x32_bf16(pA.v, vf, oA[nb], 0, 0, 0);
                oB[nb] = __builtin_amdgcn_mfma_f32_16x16x32_bf16(pB.v, vf, oB[nb], 0, 0, 0);
            }
            lA = __builtin_amdgcn_mfma_f32_16x16x32_bf16(pA.v, ones, lA, 0, 0, 0);
            lB = __builtin_amdgcn_mfma_f32_16x16x32_bf16(pB.v, ones, lB, 0, 0, 0);
        }
    }

    // ---- epilogue: normalize (l already C-layout), store bf16 ----
    const int orowA = q0 + wave * 16 + quad * 4;
    const int orowB = orowA + 64;
#pragma unroll
    for (int r = 0; r < 4; r++) {
        float invA = 1.f / lA[r];
        float invB = 1.f / lB[r];
#pragma unroll
        for (int nb = 0; nb < 4; nb++) {
            out[(size_t)(orowA + r) * DIM + h * 64 + nb * 16 + m16] = bf16_of(oA[nb][r] * invA);
            out[(size_t)(orowB + r) * DIM + h * 64 + nb * 16 + m16] = bf16_of(oB[nb][r] * invB);
        }
    }
}

// ---------------------------------------------------------------------------
extern "C" void kernel_launch(void* const* d_in, const int* in_sizes, int n_in,
                              void* d_out, int out_size, void* d_ws, size_t ws_size,
                              hipStream_t stream) {
    const float* x    = (const float*)d_in[0];
    const float* wq   = (const float*)d_in[1];
    const float* wk   = (const float*)d_in[2];
    const float* wv   = (const float*)d_in[3];
    const float* wo   = (const float*)d_in[4];
    const float* fcos = (const float*)d_in[5];
    const float* fsin = (const float*)d_in[6];

    char* ws = (char*)d_ws;
    const size_t MB = 1024 * 1024;
    unsigned short* xbf    = (unsigned short*)(ws);             //  8 MB [2048][2048]
    unsigned short* wqkvT  = (unsigned short*)(ws + 8 * MB);    // 12 MB [3072][2048]
    unsigned short* woT    = (unsigned short*)(ws + 20 * MB);   //  8 MB [2048][2048]
    unsigned short* qkvbf  = (unsigned short*)(ws + 28 * MB);   // 12 MB [2048][3072]
    unsigned short* vbt    = (unsigned short*)(ws + 40 * MB);   //  2 MB [512][2048]
    // aliases (producer runs strictly after aliased buffer is dead):
    unsigned short* qbf    = (unsigned short*)(ws + 8 * MB);    //  8 MB (over wqkvT)
    unsigned short* kbf    = (unsigned short*)(ws + 16 * MB);   //  2 MB (over wqkvT tail)
    unsigned short* attnbf = (unsigned short*)(ws);             //  8 MB (over xbf)

    // 1. convert x + transpose weights (fused)
    prep<<<4096 + 2560, 256, 0, stream>>>(x, wq, wk, wv, wo, xbf, wqkvT, woT);

    // 2. fused QKV projection (bf16 out)
    gemm_bt64<<<dim3(QKV_N / 64, S_LEN / 128), 256, 0, stream>>>(xbf, wqkvT, qkvbf,
                                                                 S_LEN, QKV_N, DIM, 1);

    // 3. RoPE + V transpose (fused)
    rope_tv<<<2560 + 256, 256, 0, stream>>>(qkvbf, qbf, kbf, vbt, fcos, fsin);

    // 4. flash attention (2 row-groups/wave, double-buffered, l-via-MFMA)
    attn_mfma6<<<dim3(16, N_HEADS), 256, 0, stream>>>(qbf, kbf, vbt, attnbf);

    // 5. output projection (fp32 out)
    gemm_bt64<<<dim3(DIM / 64, S_LEN / 128), 256, 0, stream>>>(attnbf, woT, d_out,
                                                               S_LEN, DIM, DIM, 0);
}

// Round 9
// 233.843 us; speedup vs baseline: 1.0367x; 1.0367x over previous
//
#include <hip/hip_runtime.h>
#include <hip/hip_bf16.h>

#define DIM 2048
#define S_LEN 2048
#define N_HEADS 32
#define N_KV_HEADS 8
#define HEAD_DIM 64
#define KV_DIM (N_KV_HEADS * HEAD_DIM)   // 512
#define QKV_N (DIM + 2 * KV_DIM)         // 3072
#define QSCALE 0.18033688011112042f      // 0.125 * log2(e), folded into Q at rope

typedef __attribute__((ext_vector_type(8))) short bf16x8;
typedef __attribute__((ext_vector_type(4))) float f32x4;

__device__ __forceinline__ unsigned short bf16_of(float f) {
    __hip_bfloat16 h = __float2bfloat16(f);
    return *reinterpret_cast<unsigned short*>(&h);
}
__device__ __forceinline__ float f_of_bf16(unsigned short u) {
    unsigned int x = ((unsigned int)u) << 16;
    return __uint_as_float(x);
}
__device__ __forceinline__ void gl_lds16(const void* g, void* l) {
    __builtin_amdgcn_global_load_lds((const __attribute__((address_space(1))) void*)g,
                                     (__attribute__((address_space(3))) void*)l, 16, 0, 0);
}
// pack two fp32 -> bf16x2 by truncation: one v_perm_b32
__device__ __forceinline__ unsigned int pack2tr(float lo, float hi) {
    return __builtin_amdgcn_perm(__float_as_uint(hi), __float_as_uint(lo), 0x07060302u);
}

// ---------------------------------------------------------------------------
// prep: fused x->bf16 convert (blocks 0..4095) + 4 weight transpose/converts
// (blocks 4096..6655).  All weight transposes land in [N][K=2048] bf16.
// ---------------------------------------------------------------------------
__global__ __launch_bounds__(256) void prep(const float* __restrict__ x,
                                            const float* __restrict__ wq,
                                            const float* __restrict__ wk,
                                            const float* __restrict__ wv,
                                            const float* __restrict__ wo,
                                            unsigned short* __restrict__ xbf,
                                            unsigned short* __restrict__ wqkvT,
                                            unsigned short* __restrict__ woT) {
    __shared__ float tile[64][65];
    const int t = threadIdx.x;
    int b = blockIdx.x;
    if (b < 4096) {
        int idx = b * 256 + t;
        float4 f = ((const float4*)x)[idx];
        ushort4 u;
        u.x = bf16_of(f.x); u.y = bf16_of(f.y); u.z = bf16_of(f.z); u.w = bf16_of(f.w);
        ((ushort4*)xbf)[idx] = u;
        return;
    }
    b -= 4096;
    const float* src;
    unsigned short* dst;
    int src_cols, bx, by;
    if (b < 1024)      { src = wq; dst = wqkvT;                                src_cols = DIM;    bx = b & 31;          by = b >> 5; }
    else if (b < 1280) { src = wk; dst = wqkvT + (size_t)DIM * DIM;            src_cols = KV_DIM; bx = (b - 1024) & 7;  by = (b - 1024) >> 3; }
    else if (b < 1536) { src = wv; dst = wqkvT + (size_t)(DIM + KV_DIM) * DIM; src_cols = KV_DIM; bx = (b - 1280) & 7;  by = (b - 1280) >> 3; }
    else               { src = wo; dst = woT;                                  src_cols = DIM;    bx = (b - 1536) & 31; by = (b - 1536) >> 5; }
    const int c0 = bx * 64, r0 = by * 64;
#pragma unroll
    for (int i = 0; i < 16; i++) {
        int idx = t + i * 256;
        int r = idx >> 6, c = idx & 63;
        tile[r][c] = src[(size_t)(r0 + r) * src_cols + c0 + c];
    }
    __syncthreads();
#pragma unroll
    for (int i = 0; i < 16; i++) {
        int idx = t + i * 256;
        int r = idx >> 6, c = idx & 63;
        dst[(size_t)(c0 + r) * DIM + r0 + c] = bf16_of(tile[c][r]);
    }
}

// ---------------------------------------------------------------------------
// bf16 MFMA GEMM v2: 128x128 tile, BK=64, 4 waves (each 64x64), DOUBLE-
// BUFFERED global_load_lds staging -> one barrier per BK-step, 32 MFMAs/wave
// between barriers, prefetch covers HBM latency with the compute phase.
// C[M][N] = A[M][K] @ Bt[N][K]^T.  LDS 64KB -> 2 blocks/CU.
// ---------------------------------------------------------------------------
__global__ __launch_bounds__(256) void gemm_bt128(const unsigned short* __restrict__ A,
                                                  const unsigned short* __restrict__ Bt,
                                                  void* __restrict__ Cv,
                                                  int M, int N, int K, int c_bf16) {
    __shared__ unsigned short As[2][128 * 64];
    __shared__ unsigned short Bs[2][128 * 64];
    const int tid = threadIdx.x;
    const int wave = tid >> 6, lane = tid & 63;
    const int m16 = lane & 15, quad = lane >> 4;
    const int m0 = blockIdx.y * 128, n0 = blockIdx.x * 128;
    const int wm = (wave >> 1) * 64, wn = (wave & 1) * 64;

    const int lrow = lane >> 3;
    const int gc = (lane & 7) ^ lrow;
    const unsigned short* Ab = A + (size_t)(m0 + wave * 8 + lrow) * K + gc * 8;
    const unsigned short* Bb = Bt + (size_t)(n0 + wave * 8 + lrow) * K + gc * 8;

    f32x4 acc[4][4];
#pragma unroll
    for (int mb = 0; mb < 4; mb++)
#pragma unroll
        for (int nb = 0; nb < 4; nb++) acc[mb][nb] = (f32x4){0.f, 0.f, 0.f, 0.f};

    const int n_steps = K >> 6;                    // 32 for K=2048

    // prologue: stage step 0 into buffer 0
#pragma unroll
    for (int g = 0; g < 4; g++) {
        gl_lds16(Ab + (size_t)g * 32 * K, &As[0][(g * 32 + wave * 8) * 64]);
        gl_lds16(Bb + (size_t)g * 32 * K, &Bs[0][(g * 32 + wave * 8) * 64]);
    }

    for (int i = 0; i < n_steps; i++) {
        __syncthreads();                           // buf[i&1] DMA drained; old reads done
        if (i + 1 < n_steps) {
            const int nb2 = (i + 1) & 1;
            const int k0 = (i + 1) << 6;
#pragma unroll
            for (int g = 0; g < 4; g++) {
                gl_lds16(Ab + (size_t)g * 32 * K + k0, &As[nb2][(g * 32 + wave * 8) * 64]);
                gl_lds16(Bb + (size_t)g * 32 * K + k0, &Bs[nb2][(g * 32 + wave * 8) * 64]);
            }
        }
        const unsigned short* A_ = As[i & 1];
        const unsigned short* B_ = Bs[i & 1];
#pragma unroll
        for (int ks = 0; ks < 2; ks++) {
            const int ch = (ks * 4 + quad) ^ (m16 & 7);
            bf16x8 af[4], bfr[4];
#pragma unroll
            for (int mb = 0; mb < 4; mb++) {
                af[mb]  = *(const bf16x8*)&A_[(wm + mb * 16 + m16) * 64 + ch * 8];
                bfr[mb] = *(const bf16x8*)&B_[(wn + mb * 16 + m16) * 64 + ch * 8];
            }
#pragma unroll
            for (int mb = 0; mb < 4; mb++)
#pragma unroll
                for (int nb = 0; nb < 4; nb++)
                    acc[mb][nb] = __builtin_amdgcn_mfma_f32_16x16x32_bf16(af[mb], bfr[nb], acc[mb][nb], 0, 0, 0);
        }
    }

    if (c_bf16) {
        unsigned short* C = (unsigned short*)Cv;
#pragma unroll
        for (int mb = 0; mb < 4; mb++)
#pragma unroll
            for (int nb = 0; nb < 4; nb++)
#pragma unroll
                for (int r = 0; r < 4; r++)
                    C[(size_t)(m0 + wm + mb * 16 + quad * 4 + r) * N + n0 + wn + nb * 16 + m16] =
                        bf16_of(acc[mb][nb][r]);
    } else {
        float* C = (float*)Cv;
#pragma unroll
        for (int mb = 0; mb < 4; mb++)
#pragma unroll
            for (int nb = 0; nb < 4; nb++)
#pragma unroll
                for (int r = 0; r < 4; r++)
                    C[(size_t)(m0 + wm + mb * 16 + quad * 4 + r) * N + n0 + wn + nb * 16 + m16] =
                        acc[mb][nb][r];
    }
}

// ---------------------------------------------------------------------------
// rope_tv: fused RoPE (blocks 0..2559) + V transpose-with-key-permute
// (blocks 2560..2815).  Q pre-scaled by 0.125*log2(e) (exp2 domain).
// V perm within each 128-key block matches the attention PV A-frag order.
// ---------------------------------------------------------------------------
__global__ __launch_bounds__(256) void rope_tv(const unsigned short* __restrict__ qkv,
                                               unsigned short* __restrict__ qbf,
                                               unsigned short* __restrict__ kbf,
                                               unsigned short* __restrict__ vbt,
                                               const float* __restrict__ fcos,
                                               const float* __restrict__ fsin) {
    __shared__ unsigned short tile[64][65];
    const int t = threadIdx.x;
    int b = blockIdx.x;
    if (b < 2560) {
        int idx = b * 256 + t;
        const int nq = S_LEN * N_HEADS * 8;
        int s, j, srcoff, dstoff;
        unsigned short* dst;
        float osc;
        if (idx < nq) {
            s = idx >> 8;
            int rem = idx & 255;
            int h = rem >> 3;
            j = rem & 7;
            srcoff = s * QKV_N + h * 64 + j * 8;
            dstoff = s * DIM + h * 64 + j * 8;
            dst = qbf;
            osc = QSCALE;
        } else {
            int t2 = idx - nq;
            s = t2 >> 6;
            int rem = t2 & 63;
            int h = rem >> 3;
            j = rem & 7;
            srcoff = s * QKV_N + DIM + h * 64 + j * 8;
            dstoff = s * KV_DIM + h * 64 + j * 8;
            dst = kbf;
            osc = 1.0f;
        }
        bf16x8 v8 = *(const bf16x8*)&qkv[srcoff];
        float4 c4 = *(const float4*)&fcos[s * 32 + j * 4];
        float4 s4 = *(const float4*)&fsin[s * 32 + j * 4];
        float cs[4] = {c4.x, c4.y, c4.z, c4.w};
        float sn[4] = {s4.x, s4.y, s4.z, s4.w};
        bf16x8 o;
#pragma unroll
        for (int p = 0; p < 4; p++) {
            float a = f_of_bf16((unsigned short)v8[2 * p]);
            float bb = f_of_bf16((unsigned short)v8[2 * p + 1]);
            o[2 * p]     = (short)bf16_of((a * cs[p] - bb * sn[p]) * osc);
            o[2 * p + 1] = (short)bf16_of((a * sn[p] + bb * cs[p]) * osc);
        }
        *(bf16x8*)&dst[dstoff] = o;
        return;
    }
    b -= 2560;                                    // 0..255  (8 x 32)
    const int d0 = (b & 7) * 64;
    const int s0 = (b >> 3) * 64;
#pragma unroll
    for (int i = 0; i < 16; i++) {
        int idx = t + i * 256;
        int r = idx >> 6, c = idx & 63;
        tile[r][c] = qkv[(size_t)(s0 + r) * QKV_N + DIM + KV_DIM + d0 + c];
    }
    __syncthreads();
#pragma unroll
    for (int i = 0; i < 16; i++) {
        int idx = t + i * 256;
        int r = idx >> 6, c = idx & 63;
        int key = s0 + c;
        int kl = key & 127;
        int kp = (kl & 0x60) | ((kl & 0x0C) << 1) | ((kl & 0x10) >> 2) | (kl & 3);
        vbt[(size_t)(d0 + r) * S_LEN + (key & ~127) + kp] = tile[c][r];
    }
}

// ---------------------------------------------------------------------------
// Flash attention v5 (reverted R6 config — best measured: 42.7us).
// Block = (head, paired q-tiles qt=31-bx then qt=bx) -> uniform 17 iters.
//   - double-buffered K/V DMA staging: ONE barrier/iter
//   - l via MFMA ones-trick (row-sum of P as extra accumulator)
//   - P packed with v_perm_b32 truncation
//   - S^T operand-swap + in-register P + exp2-domain softmax
// ---------------------------------------------------------------------------
__global__ __launch_bounds__(256) void attn_mfma5(const unsigned short* __restrict__ qb,
                                                  const unsigned short* __restrict__ kb,
                                                  const unsigned short* __restrict__ vbt,
                                                  unsigned short* __restrict__ out) {
    const int h  = blockIdx.y;
    const int bx = blockIdx.x;                    // 0..15
    const int kh = h >> 2;
    const int tid  = threadIdx.x;
    const int wave = tid >> 6;
    const int lane = tid & 63;
    const int m16  = lane & 15;
    const int quad = lane >> 4;

    __shared__ unsigned short Ks[2][128 * 64];    // [key][dim], chunk-swizzled
    __shared__ unsigned short Vt[2][64 * 128];    // [dim][key(perm)], chunk-swizzled

    const int lrow8 = lane >> 3;
    const int kc    = (lane & 7) ^ lrow8;
    const int lrow4 = lane >> 4;
    const int vc    = (lane & 15) ^ ((wave * 4 + lrow4) & 7);

    const unsigned short* Kbase = kb + (size_t)kh * 64 + (size_t)(wave * 8 + lrow8) * KV_DIM + kc * 8;
    const unsigned short* Vbase = vbt + (size_t)(kh * 64 + wave * 4 + lrow4) * S_LEN + vc * 8;

    bf16x8 ones;
#pragma unroll
    for (int i = 0; i < 8; i++) ones[i] = (short)0x3F80;   // 1.0 bf16

#pragma unroll
    for (int half = 0; half < 2; half++) {
        const int qt = half ? bx : (31 - bx);
        const int q0 = qt * 64;
        const int n_iter = (qt >> 1) + 1;

        bf16x8 qa[2];
        {
            const int qrow = q0 + wave * 16 + m16;
#pragma unroll
            for (int ks = 0; ks < 2; ks++)
                qa[ks] = *(const bf16x8*)&qb[(size_t)qrow * DIM + h * 64 + ks * 32 + quad * 8];
        }

        f32x4 o_acc[4];
#pragma unroll
        for (int nb = 0; nb < 4; nb++) o_acc[nb] = (f32x4){0.f, 0.f, 0.f, 0.f};
        f32x4 l_acc = (f32x4){0.f, 0.f, 0.f, 0.f};
        float m_s = -1e30f;
        const int qrow_lane = q0 + wave * 16 + m16;
        const int orow_base = q0 + wave * 16 + quad * 4;

        if (half) __syncthreads();   // all waves done reading previous half's buffers

        // prologue: stage tile 0 into buffer 0
#pragma unroll
        for (int g = 0; g < 4; g++) {
            gl_lds16(Kbase + (size_t)(g * 32) * KV_DIM, &Ks[0][(g * 32 + wave * 8) * 64]);
            gl_lds16(Vbase + (size_t)g * 16 * S_LEN, &Vt[0][(g * 16 + wave * 4) * 128]);
        }

        for (int kt = 0; kt < n_iter; kt++) {
            __syncthreads();                       // buf[kt&1] DMA drained; prev reads done
            if (kt + 1 < n_iter) {
                const int nb2 = (kt + 1) & 1;
#pragma unroll
                for (int g = 0; g < 4; g++) {
                    gl_lds16(Kbase + (size_t)((kt + 1) * 128 + g * 32) * KV_DIM,
                             &Ks[nb2][(g * 32 + wave * 8) * 64]);
                    gl_lds16(Vbase + (size_t)g * 16 * S_LEN + (kt + 1) * 128,
                             &Vt[nb2][(g * 16 + wave * 4) * 128]);
                }
            }
            const unsigned short* K_ = Ks[kt & 1];
            const unsigned short* V_ = Vt[kt & 1];

            // ---- S^T = K Q^T : sc[cb] holds keys cb*16+quad*4+r, qrow m16 ----
            f32x4 sc[8];
#pragma unroll
            for (int cb = 0; cb < 8; cb++) sc[cb] = (f32x4){0.f, 0.f, 0.f, 0.f};
#pragma unroll
            for (int ks = 0; ks < 2; ks++) {
                const int slot = (ks * 4 + quad) ^ (m16 & 7);
#pragma unroll
                for (int cb = 0; cb < 8; cb++) {
                    bf16x8 kf = *(const bf16x8*)&K_[(cb * 16 + m16) * 64 + slot * 8];
                    sc[cb] = __builtin_amdgcn_mfma_f32_16x16x32_bf16(kf, qa[ks], sc[cb], 0, 0, 0);
                }
            }

            // ---- causal mask (last tile of this q-tile only) ----
            if (kt == n_iter - 1) {
#pragma unroll
                for (int cb = 0; cb < 8; cb++) {
                    int key = kt * 128 + cb * 16 + quad * 4;
#pragma unroll
                    for (int r = 0; r < 4; r++)
                        if (key + r > qrow_lane) sc[cb][r] = -1e30f;
                }
            }

            // ---- online softmax (exp2 domain; all 32 values are row m16) ----
            float rmax = fmaxf(fmaxf(sc[0][0], sc[0][1]), fmaxf(sc[0][2], sc[0][3]));
#pragma unroll
            for (int cb = 1; cb < 8; cb++) {
                float c1 = fmaxf(fmaxf(sc[cb][0], sc[cb][1]), fmaxf(sc[cb][2], sc[cb][3]));
                rmax = fmaxf(rmax, c1);
            }
            rmax = fmaxf(rmax, __shfl_xor(rmax, 16, 64));
            rmax = fmaxf(rmax, __shfl_xor(rmax, 32, 64));

            float mnew = fmaxf(m_s, rmax);
            float alpha = __builtin_amdgcn_exp2f(m_s - mnew);
            m_s = mnew;

#pragma unroll
            for (int cb = 0; cb < 8; cb++)
#pragma unroll
                for (int r = 0; r < 4; r++)
                    sc[cb][r] = __builtin_amdgcn_exp2f(sc[cb][r] - mnew);

            // ---- pack P fragments (truncation, 1 v_perm each) ----
            unsigned int P01[8], P23[8];
#pragma unroll
            for (int cb = 0; cb < 8; cb++) {
                P01[cb] = pack2tr(sc[cb][0], sc[cb][1]);
                P23[cb] = pack2tr(sc[cb][2], sc[cb][3]);
            }

            // ---- rescale O and l by alpha of row quad*4+r ----
#pragma unroll
            for (int r = 0; r < 4; r++) {
                float a_r = __shfl(alpha, quad * 4 + r, 64);
#pragma unroll
                for (int nb = 0; nb < 4; nb++) o_acc[nb][r] *= a_r;
                l_acc[r] *= a_r;
            }

            // ---- O += P V (and l += P @ ones) ----
#pragma unroll
            for (int ks = 0; ks < 4; ks++) {
                union { unsigned int u[4]; bf16x8 v; } pa;
                pa.u[0] = P01[2 * ks];     pa.u[1] = P23[2 * ks];
                pa.u[2] = P01[2 * ks + 1]; pa.u[3] = P23[2 * ks + 1];
                const int slot = (ks * 4 + quad) ^ (m16 & 7);
#pragma unroll
                for (int nb = 0; nb < 4; nb++) {
                    bf16x8 vf = *(const bf16x8*)&V_[(nb * 16 + m16) * 128 + slot * 8];
                    o_acc[nb] = __builtin_amdgcn_mfma_f32_16x16x32_bf16(pa.v, vf, o_acc[nb], 0, 0, 0);
                }
                l_acc = __builtin_amdgcn_mfma_f32_16x16x32_bf16(pa.v, ones, l_acc, 0, 0, 0);
            }
        }

        // ---- epilogue: normalize by l (already C-layout), store bf16 ----
#pragma unroll
        for (int r = 0; r < 4; r++) {
            float inv_l = 1.f / l_acc[r];
#pragma unroll
            for (int nb = 0; nb < 4; nb++)
                out[(size_t)(orow_base + r) * DIM + h * 64 + nb * 16 + m16] =
                    bf16_of(o_acc[nb][r] * inv_l);
        }
    }
}

// ---------------------------------------------------------------------------
extern "C" void kernel_launch(void* const* d_in, const int* in_sizes, int n_in,
                              void* d_out, int out_size, void* d_ws, size_t ws_size,
                              hipStream_t stream) {
    const float* x    = (const float*)d_in[0];
    const float* wq   = (const float*)d_in[1];
    const float* wk   = (const float*)d_in[2];
    const float* wv   = (const float*)d_in[3];
    const float* wo   = (const float*)d_in[4];
    const float* fcos = (const float*)d_in[5];
    const float* fsin = (const float*)d_in[6];

    char* ws = (char*)d_ws;
    const size_t MB = 1024 * 1024;
    unsigned short* xbf    = (unsigned short*)(ws);             //  8 MB [2048][2048]
    unsigned short* wqkvT  = (unsigned short*)(ws + 8 * MB);    // 12 MB [3072][2048]
    unsigned short* woT    = (unsigned short*)(ws + 20 * MB);   //  8 MB [2048][2048]
    unsigned short* qkvbf  = (unsigned short*)(ws + 28 * MB);   // 12 MB [2048][3072]
    unsigned short* vbt    = (unsigned short*)(ws + 40 * MB);   //  2 MB [512][2048]
    // aliases (producer runs strictly after aliased buffer is dead):
    unsigned short* qbf    = (unsigned short*)(ws + 8 * MB);    //  8 MB (over wqkvT)
    unsigned short* kbf    = (unsigned short*)(ws + 16 * MB);   //  2 MB (over wqkvT tail)
    unsigned short* attnbf = (unsigned short*)(ws);             //  8 MB (over xbf)

    // 1. convert x + transpose weights (fused)
    prep<<<4096 + 2560, 256, 0, stream>>>(x, wq, wk, wv, wo, xbf, wqkvT, woT);

    // 2. fused QKV projection (bf16 out) — 128x128 dbuf GEMM, 384 blocks
    gemm_bt128<<<dim3(QKV_N / 128, S_LEN / 128), 256, 0, stream>>>(xbf, wqkvT, qkvbf,
                                                                   S_LEN, QKV_N, DIM, 1);

    // 3. RoPE + V transpose (fused)
    rope_tv<<<2560 + 256, 256, 0, stream>>>(qkvbf, qbf, kbf, vbt, fcos, fsin);

    // 4. flash attention (R6 config: paired q-tiles, dbuf, l-via-MFMA)
    attn_mfma5<<<dim3(16, N_HEADS), 256, 0, stream>>>(qbf, kbf, vbt, attnbf);

    // 5. output projection (fp32 out) — 256 blocks, uniform 1/CU
    gemm_bt128<<<dim3(DIM / 128, S_LEN / 128), 256, 0, stream>>>(attnbf, woT, d_out,
                                                                 S_LEN, DIM, DIM, 0);
}

// Round 10
// 231.052 us; speedup vs baseline: 1.0492x; 1.0121x over previous
//
#include <hip/hip_runtime.h>
#include <hip/hip_bf16.h>

#define DIM 2048
#define S_LEN 2048
#define N_HEADS 32
#define N_KV_HEADS 8
#define HEAD_DIM 64
#define KV_DIM (N_KV_HEADS * HEAD_DIM)   // 512
#define QKV_N (DIM + 2 * KV_DIM)         // 3072
#define QSCALE 0.18033688011112042f      // 0.125 * log2(e), folded into Q rope coeffs

typedef __attribute__((ext_vector_type(8))) short bf16x8;
typedef __attribute__((ext_vector_type(4))) float f32x4;

__device__ __forceinline__ unsigned short bf16_of(float f) {
    __hip_bfloat16 h = __float2bfloat16(f);
    return *reinterpret_cast<unsigned short*>(&h);
}
__device__ __forceinline__ float f_of_bf16(unsigned short u) {
    unsigned int x = ((unsigned int)u) << 16;
    return __uint_as_float(x);
}
__device__ __forceinline__ void gl_lds16(const void* g, void* l) {
    __builtin_amdgcn_global_load_lds((const __attribute__((address_space(1))) void*)g,
                                     (__attribute__((address_space(3))) void*)l, 16, 0, 0);
}
// pack two fp32 -> bf16x2 by truncation: one v_perm_b32
__device__ __forceinline__ unsigned int pack2tr(float lo, float hi) {
    return __builtin_amdgcn_perm(__float_as_uint(hi), __float_as_uint(lo), 0x07060302u);
}

// ---------------------------------------------------------------------------
// prep: fused x->bf16 convert (blocks 0..4095) + 4 weight transpose/converts
// (blocks 4096..6655).  All weight transposes land in [N][K=2048] bf16.
// ---------------------------------------------------------------------------
__global__ __launch_bounds__(256) void prep(const float* __restrict__ x,
                                            const float* __restrict__ wq,
                                            const float* __restrict__ wk,
                                            const float* __restrict__ wv,
                                            const float* __restrict__ wo,
                                            unsigned short* __restrict__ xbf,
                                            unsigned short* __restrict__ wqkvT,
                                            unsigned short* __restrict__ woT) {
    __shared__ float tile[64][65];
    const int t = threadIdx.x;
    int b = blockIdx.x;
    if (b < 4096) {
        int idx = b * 256 + t;
        float4 f = ((const float4*)x)[idx];
        ushort4 u;
        u.x = bf16_of(f.x); u.y = bf16_of(f.y); u.z = bf16_of(f.z); u.w = bf16_of(f.w);
        ((ushort4*)xbf)[idx] = u;
        return;
    }
    b -= 4096;
    const float* src;
    unsigned short* dst;
    int src_cols, bx, by;
    if (b < 1024)      { src = wq; dst = wqkvT;                                src_cols = DIM;    bx = b & 31;          by = b >> 5; }
    else if (b < 1280) { src = wk; dst = wqkvT + (size_t)DIM * DIM;            src_cols = KV_DIM; bx = (b - 1024) & 7;  by = (b - 1024) >> 3; }
    else if (b < 1536) { src = wv; dst = wqkvT + (size_t)(DIM + KV_DIM) * DIM; src_cols = KV_DIM; bx = (b - 1280) & 7;  by = (b - 1280) >> 3; }
    else               { src = wo; dst = woT;                                  src_cols = DIM;    bx = (b - 1536) & 31; by = (b - 1536) >> 5; }
    const int c0 = bx * 64, r0 = by * 64;
#pragma unroll
    for (int i = 0; i < 16; i++) {
        int idx = t + i * 256;
        int r = idx >> 6, c = idx & 63;
        tile[r][c] = src[(size_t)(r0 + r) * src_cols + c0 + c];
    }
    __syncthreads();
#pragma unroll
    for (int i = 0; i < 16; i++) {
        int idx = t + i * 256;
        int r = idx >> 6, c = idx & 63;
        dst[(size_t)(c0 + r) * DIM + r0 + c] = bf16_of(tile[c][r]);
    }
}

// ---------------------------------------------------------------------------
// QKV GEMM with fused RoPE epilogue.  128(M) x 64(N) tile, BK=64, 4 waves,
// double-buffered DMA staging (one barrier per BK-step).  Grid (48,16)=768
// blocks = exactly 3/CU.  Epilogue: Q cols rope'd (scaled by QSCALE) -> qbf,
// K cols rope'd -> kbf, V cols plain -> vbf.  RoPE pair partner lives in the
// adjacent m16 lane: one __shfl_xor(v,1).
// ---------------------------------------------------------------------------
__global__ __launch_bounds__(256) void gemm_qkv(const unsigned short* __restrict__ A,
                                                const unsigned short* __restrict__ Bt,
                                                unsigned short* __restrict__ qbf,
                                                unsigned short* __restrict__ kbf,
                                                unsigned short* __restrict__ vbf,
                                                const float* __restrict__ fcos,
                                                const float* __restrict__ fsin) {
    __shared__ unsigned short As[2][128 * 64];
    __shared__ unsigned short Bs[2][64 * 64];
    const int tid = threadIdx.x;
    const int wave = tid >> 6, lane = tid & 63;
    const int m16 = lane & 15, quad = lane >> 4;
    const int m0 = blockIdx.y * 128, n0 = blockIdx.x * 64;
    const int wm = (wave >> 1) * 64, wn = (wave & 1) * 32;
    const int K = DIM;

    const int lrow = lane >> 3;
    const int gc = (lane & 7) ^ lrow;
    const unsigned short* Ab = A + (size_t)(m0 + wave * 8 + lrow) * K + gc * 8;
    const unsigned short* Bb = Bt + (size_t)(n0 + wave * 8 + lrow) * K + gc * 8;

    f32x4 acc[4][2];
#pragma unroll
    for (int mb = 0; mb < 4; mb++)
#pragma unroll
        for (int nb = 0; nb < 2; nb++) acc[mb][nb] = (f32x4){0.f, 0.f, 0.f, 0.f};

    // prologue: stage step 0 into buffer 0
#pragma unroll
    for (int g = 0; g < 4; g++)
        gl_lds16(Ab + (size_t)g * 32 * K, &As[0][(g * 32 + wave * 8) * 64]);
#pragma unroll
    for (int g = 0; g < 2; g++)
        gl_lds16(Bb + (size_t)g * 32 * K, &Bs[0][(g * 32 + wave * 8) * 64]);

    const int n_steps = K >> 6;                    // 32
    for (int i = 0; i < n_steps; i++) {
        __syncthreads();
        if (i + 1 < n_steps) {
            const int nb2 = (i + 1) & 1;
            const int k0 = (i + 1) << 6;
#pragma unroll
            for (int g = 0; g < 4; g++)
                gl_lds16(Ab + (size_t)g * 32 * K + k0, &As[nb2][(g * 32 + wave * 8) * 64]);
#pragma unroll
            for (int g = 0; g < 2; g++)
                gl_lds16(Bb + (size_t)g * 32 * K + k0, &Bs[nb2][(g * 32 + wave * 8) * 64]);
        }
        const unsigned short* A_ = As[i & 1];
        const unsigned short* B_ = Bs[i & 1];
#pragma unroll
        for (int ks = 0; ks < 2; ks++) {
            const int ch = (ks * 4 + quad) ^ (m16 & 7);
            bf16x8 af[4], bfr[2];
#pragma unroll
            for (int mb = 0; mb < 4; mb++)
                af[mb] = *(const bf16x8*)&A_[(wm + mb * 16 + m16) * 64 + ch * 8];
#pragma unroll
            for (int nb = 0; nb < 2; nb++)
                bfr[nb] = *(const bf16x8*)&B_[(wn + nb * 16 + m16) * 64 + ch * 8];
#pragma unroll
            for (int mb = 0; mb < 4; mb++)
#pragma unroll
                for (int nb = 0; nb < 2; nb++)
                    acc[mb][nb] = __builtin_amdgcn_mfma_f32_16x16x32_bf16(af[mb], bfr[nb], acc[mb][nb], 0, 0, 0);
        }
    }

    // ---- epilogue ----
    if (n0 >= DIM + KV_DIM) {
        // V: plain bf16 store to vbf [S][512]
#pragma unroll
        for (int mb = 0; mb < 4; mb++)
#pragma unroll
            for (int nb = 0; nb < 2; nb++)
#pragma unroll
                for (int r = 0; r < 4; r++)
                    vbf[(size_t)(m0 + wm + mb * 16 + quad * 4 + r) * KV_DIM +
                        (n0 - DIM - KV_DIM) + wn + nb * 16 + m16] = bf16_of(acc[mb][nb][r]);
        return;
    }
    // Q or K: fused RoPE.  col parity decides the pair role.
    const bool is_q = (n0 < DIM);
    const float osc = is_q ? QSCALE : 1.0f;
    unsigned short* dst = is_q ? qbf : kbf;
    const int dst_stride = is_q ? DIM : KV_DIM;
    const int cbase = is_q ? n0 : (n0 - DIM);
    const int odd = m16 & 1;
#pragma unroll
    for (int nb = 0; nb < 2; nb++) {
        const int col = cbase + wn + nb * 16 + m16;
        const int fi = (col >> 1) & 31;           // pair index within head
#pragma unroll
        for (int mb = 0; mb < 4; mb++) {
#pragma unroll
            for (int r = 0; r < 4; r++) {
                const int s = m0 + wm + mb * 16 + quad * 4 + r;
                float v = acc[mb][nb][r];
                float p = __shfl_xor(v, 1, 64);   // pair partner (adjacent col)
                float c = fcos[s * 32 + fi] * osc;
                float sn = fsin[s * 32 + fi] * osc;
                float o = odd ? (p * sn + v * c) : (v * c - p * sn);
                dst[(size_t)s * dst_stride + col] = bf16_of(o);
            }
        }
    }
}

// ---------------------------------------------------------------------------
// generic bf16 GEMM (out-projection): 128x64 tile, BK=64, double-buffered.
// C[M][N] = A[M][K] @ Bt[N][K]^T, fp32 or bf16 out.
// ---------------------------------------------------------------------------
__global__ __launch_bounds__(256) void gemm_bt64d(const unsigned short* __restrict__ A,
                                                  const unsigned short* __restrict__ Bt,
                                                  void* __restrict__ Cv,
                                                  int M, int N, int K, int c_bf16) {
    __shared__ unsigned short As[2][128 * 64];
    __shared__ unsigned short Bs[2][64 * 64];
    const int tid = threadIdx.x;
    const int wave = tid >> 6, lane = tid & 63;
    const int m16 = lane & 15, quad = lane >> 4;
    const int m0 = blockIdx.y * 128, n0 = blockIdx.x * 64;
    const int wm = (wave >> 1) * 64, wn = (wave & 1) * 32;

    const int lrow = lane >> 3;
    const int gc = (lane & 7) ^ lrow;
    const unsigned short* Ab = A + (size_t)(m0 + wave * 8 + lrow) * K + gc * 8;
    const unsigned short* Bb = Bt + (size_t)(n0 + wave * 8 + lrow) * K + gc * 8;

    f32x4 acc[4][2];
#pragma unroll
    for (int mb = 0; mb < 4; mb++)
#pragma unroll
        for (int nb = 0; nb < 2; nb++) acc[mb][nb] = (f32x4){0.f, 0.f, 0.f, 0.f};

#pragma unroll
    for (int g = 0; g < 4; g++)
        gl_lds16(Ab + (size_t)g * 32 * K, &As[0][(g * 32 + wave * 8) * 64]);
#pragma unroll
    for (int g = 0; g < 2; g++)
        gl_lds16(Bb + (size_t)g * 32 * K, &Bs[0][(g * 32 + wave * 8) * 64]);

    const int n_steps = K >> 6;
    for (int i = 0; i < n_steps; i++) {
        __syncthreads();
        if (i + 1 < n_steps) {
            const int nb2 = (i + 1) & 1;
            const int k0 = (i + 1) << 6;
#pragma unroll
            for (int g = 0; g < 4; g++)
                gl_lds16(Ab + (size_t)g * 32 * K + k0, &As[nb2][(g * 32 + wave * 8) * 64]);
#pragma unroll
            for (int g = 0; g < 2; g++)
                gl_lds16(Bb + (size_t)g * 32 * K + k0, &Bs[nb2][(g * 32 + wave * 8) * 64]);
        }
        const unsigned short* A_ = As[i & 1];
        const unsigned short* B_ = Bs[i & 1];
#pragma unroll
        for (int ks = 0; ks < 2; ks++) {
            const int ch = (ks * 4 + quad) ^ (m16 & 7);
            bf16x8 af[4], bfr[2];
#pragma unroll
            for (int mb = 0; mb < 4; mb++)
                af[mb] = *(const bf16x8*)&A_[(wm + mb * 16 + m16) * 64 + ch * 8];
#pragma unroll
            for (int nb = 0; nb < 2; nb++)
                bfr[nb] = *(const bf16x8*)&B_[(wn + nb * 16 + m16) * 64 + ch * 8];
#pragma unroll
            for (int mb = 0; mb < 4; mb++)
#pragma unroll
                for (int nb = 0; nb < 2; nb++)
                    acc[mb][nb] = __builtin_amdgcn_mfma_f32_16x16x32_bf16(af[mb], bfr[nb], acc[mb][nb], 0, 0, 0);
        }
    }

    if (c_bf16) {
        unsigned short* C = (unsigned short*)Cv;
#pragma unroll
        for (int mb = 0; mb < 4; mb++)
#pragma unroll
            for (int nb = 0; nb < 2; nb++)
#pragma unroll
                for (int r = 0; r < 4; r++)
                    C[(size_t)(m0 + wm + mb * 16 + quad * 4 + r) * N + n0 + wn + nb * 16 + m16] =
                        bf16_of(acc[mb][nb][r]);
    } else {
        float* C = (float*)Cv;
#pragma unroll
        for (int mb = 0; mb < 4; mb++)
#pragma unroll
            for (int nb = 0; nb < 2; nb++)
#pragma unroll
                for (int r = 0; r < 4; r++)
                    C[(size_t)(m0 + wm + mb * 16 + quad * 4 + r) * N + n0 + wn + nb * 16 + m16] =
                        acc[mb][nb][r];
    }
}

// ---------------------------------------------------------------------------
// Transpose V (bf16 [S][512]) -> vbt [512][2048] with the key bit-permute
// within each 128-key block matching the attention PV A-frag order.
// ---------------------------------------------------------------------------
__global__ __launch_bounds__(256) void transpose_v(const unsigned short* __restrict__ vbf,
                                                   unsigned short* __restrict__ vbt) {
    __shared__ unsigned short tile[64][65];
    const int t = threadIdx.x;
    const int d0 = blockIdx.x * 64;
    const int s0 = blockIdx.y * 64;
#pragma unroll
    for (int i = 0; i < 16; i++) {
        int idx = t + i * 256;
        int r = idx >> 6, c = idx & 63;
        tile[r][c] = vbf[(size_t)(s0 + r) * KV_DIM + d0 + c];
    }
    __syncthreads();
#pragma unroll
    for (int i = 0; i < 16; i++) {
        int idx = t + i * 256;
        int r = idx >> 6, c = idx & 63;
        int key = s0 + c;
        int kl = key & 127;
        int kp = (kl & 0x60) | ((kl & 0x0C) << 1) | ((kl & 0x10) >> 2) | (kl & 3);
        vbt[(size_t)(d0 + r) * S_LEN + (key & ~127) + kp] = tile[c][r];
    }
}

// ---------------------------------------------------------------------------
// Flash attention v5 (best measured config: 42.7us).
// Block = (head, paired q-tiles qt=31-bx then qt=bx) -> uniform 17 iters.
// dbuf DMA staging, l via MFMA ones, v_perm P pack, S^T swap, exp2 softmax.
// ---------------------------------------------------------------------------
__global__ __launch_bounds__(256) void attn_mfma5(const unsigned short* __restrict__ qb,
                                                  const unsigned short* __restrict__ kb,
                                                  const unsigned short* __restrict__ vbt,
                                                  unsigned short* __restrict__ out) {
    const int h  = blockIdx.y;
    const int bx = blockIdx.x;                    // 0..15
    const int kh = h >> 2;
    const int tid  = threadIdx.x;
    const int wave = tid >> 6;
    const int lane = tid & 63;
    const int m16  = lane & 15;
    const int quad = lane >> 4;

    __shared__ unsigned short Ks[2][128 * 64];    // [key][dim], chunk-swizzled
    __shared__ unsigned short Vt[2][64 * 128];    // [dim][key(perm)], chunk-swizzled

    const int lrow8 = lane >> 3;
    const int kc    = (lane & 7) ^ lrow8;
    const int lrow4 = lane >> 4;
    const int vc    = (lane & 15) ^ ((wave * 4 + lrow4) & 7);

    const unsigned short* Kbase = kb + (size_t)kh * 64 + (size_t)(wave * 8 + lrow8) * KV_DIM + kc * 8;
    const unsigned short* Vbase = vbt + (size_t)(kh * 64 + wave * 4 + lrow4) * S_LEN + vc * 8;

    bf16x8 ones;
#pragma unroll
    for (int i = 0; i < 8; i++) ones[i] = (short)0x3F80;   // 1.0 bf16

#pragma unroll
    for (int half = 0; half < 2; half++) {
        const int qt = half ? bx : (31 - bx);
        const int q0 = qt * 64;
        const int n_iter = (qt >> 1) + 1;

        bf16x8 qa[2];
        {
            const int qrow = q0 + wave * 16 + m16;
#pragma unroll
            for (int ks = 0; ks < 2; ks++)
                qa[ks] = *(const bf16x8*)&qb[(size_t)qrow * DIM + h * 64 + ks * 32 + quad * 8];
        }

        f32x4 o_acc[4];
#pragma unroll
        for (int nb = 0; nb < 4; nb++) o_acc[nb] = (f32x4){0.f, 0.f, 0.f, 0.f};
        f32x4 l_acc = (f32x4){0.f, 0.f, 0.f, 0.f};
        float m_s = -1e30f;
        const int qrow_lane = q0 + wave * 16 + m16;
        const int orow_base = q0 + wave * 16 + quad * 4;

        if (half) __syncthreads();   // all waves done reading previous half's buffers

        // prologue: stage tile 0 into buffer 0
#pragma unroll
        for (int g = 0; g < 4; g++) {
            gl_lds16(Kbase + (size_t)(g * 32) * KV_DIM, &Ks[0][(g * 32 + wave * 8) * 64]);
            gl_lds16(Vbase + (size_t)g * 16 * S_LEN, &Vt[0][(g * 16 + wave * 4) * 128]);
        }

        for (int kt = 0; kt < n_iter; kt++) {
            __syncthreads();                       // buf[kt&1] DMA drained; prev reads done
            if (kt + 1 < n_iter) {
                const int nb2 = (kt + 1) & 1;
#pragma unroll
                for (int g = 0; g < 4; g++) {
                    gl_lds16(Kbase + (size_t)((kt + 1) * 128 + g * 32) * KV_DIM,
                             &Ks[nb2][(g * 32 + wave * 8) * 64]);
                    gl_lds16(Vbase + (size_t)g * 16 * S_LEN + (kt + 1) * 128,
                             &Vt[nb2][(g * 16 + wave * 4) * 128]);
                }
            }
            const unsigned short* K_ = Ks[kt & 1];
            const unsigned short* V_ = Vt[kt & 1];

            // ---- S^T = K Q^T : sc[cb] holds keys cb*16+quad*4+r, qrow m16 ----
            f32x4 sc[8];
#pragma unroll
            for (int cb = 0; cb < 8; cb++) sc[cb] = (f32x4){0.f, 0.f, 0.f, 0.f};
#pragma unroll
            for (int ks = 0; ks < 2; ks++) {
                const int slot = (ks * 4 + quad) ^ (m16 & 7);
#pragma unroll
                for (int cb = 0; cb < 8; cb++) {
                    bf16x8 kf = *(const bf16x8*)&K_[(cb * 16 + m16) * 64 + slot * 8];
                    sc[cb] = __builtin_amdgcn_mfma_f32_16x16x32_bf16(kf, qa[ks], sc[cb], 0, 0, 0);
                }
            }

            // ---- causal mask (last tile of this q-tile only) ----
            if (kt == n_iter - 1) {
#pragma unroll
                for (int cb = 0; cb < 8; cb++) {
                    int key = kt * 128 + cb * 16 + quad * 4;
#pragma unroll
                    for (int r = 0; r < 4; r++)
                        if (key + r > qrow_lane) sc[cb][r] = -1e30f;
                }
            }

            // ---- online softmax (exp2 domain; all 32 values are row m16) ----
            float rmax = fmaxf(fmaxf(sc[0][0], sc[0][1]), fmaxf(sc[0][2], sc[0][3]));
#pragma unroll
            for (int cb = 1; cb < 8; cb++) {
                float c1 = fmaxf(fmaxf(sc[cb][0], sc[cb][1]), fmaxf(sc[cb][2], sc[cb][3]));
                rmax = fmaxf(rmax, c1);
            }
            rmax = fmaxf(rmax, __shfl_xor(rmax, 16, 64));
            rmax = fmaxf(rmax, __shfl_xor(rmax, 32, 64));

            float mnew = fmaxf(m_s, rmax);
            float alpha = __builtin_amdgcn_exp2f(m_s - mnew);
            m_s = mnew;

#pragma unroll
            for (int cb = 0; cb < 8; cb++)
#pragma unroll
                for (int r = 0; r < 4; r++)
                    sc[cb][r] = __builtin_amdgcn_exp2f(sc[cb][r] - mnew);

            // ---- pack P fragments (truncation, 1 v_perm each) ----
            unsigned int P01[8], P23[8];
#pragma unroll
            for (int cb = 0; cb < 8; cb++) {
                P01[cb] = pack2tr(sc[cb][0], sc[cb][1]);
                P23[cb] = pack2tr(sc[cb][2], sc[cb][3]);
            }

            // ---- rescale O and l by alpha of row quad*4+r ----
#pragma unroll
            for (int r = 0; r < 4; r++) {
                float a_r = __shfl(alpha, quad * 4 + r, 64);
#pragma unroll
                for (int nb = 0; nb < 4; nb++) o_acc[nb][r] *= a_r;
                l_acc[r] *= a_r;
            }

            // ---- O += P V (and l += P @ ones) ----
#pragma unroll
            for (int ks = 0; ks < 4; ks++) {
                union { unsigned int u[4]; bf16x8 v; } pa;
                pa.u[0] = P01[2 * ks];     pa.u[1] = P23[2 * ks];
                pa.u[2] = P01[2 * ks + 1]; pa.u[3] = P23[2 * ks + 1];
                const int slot = (ks * 4 + quad) ^ (m16 & 7);
#pragma unroll
                for (int nb = 0; nb < 4; nb++) {
                    bf16x8 vf = *(const bf16x8*)&V_[(nb * 16 + m16) * 128 + slot * 8];
                    o_acc[nb] = __builtin_amdgcn_mfma_f32_16x16x32_bf16(pa.v, vf, o_acc[nb], 0, 0, 0);
                }
                l_acc = __builtin_amdgcn_mfma_f32_16x16x32_bf16(pa.v, ones, l_acc, 0, 0, 0);
            }
        }

        // ---- epilogue: normalize by l (already C-layout), store bf16 ----
#pragma unroll
        for (int r = 0; r < 4; r++) {
            float inv_l = 1.f / l_acc[r];
#pragma unroll
            for (int nb = 0; nb < 4; nb++)
                out[(size_t)(orow_base + r) * DIM + h * 64 + nb * 16 + m16] =
                    bf16_of(o_acc[nb][r] * inv_l);
        }
    }
}

// ---------------------------------------------------------------------------
extern "C" void kernel_launch(void* const* d_in, const int* in_sizes, int n_in,
                              void* d_out, int out_size, void* d_ws, size_t ws_size,
                              hipStream_t stream) {
    const float* x    = (const float*)d_in[0];
    const float* wq   = (const float*)d_in[1];
    const float* wk   = (const float*)d_in[2];
    const float* wv   = (const float*)d_in[3];
    const float* wo   = (const float*)d_in[4];
    const float* fcos = (const float*)d_in[5];
    const float* fsin = (const float*)d_in[6];

    char* ws = (char*)d_ws;
    const size_t MB = 1024 * 1024;
    unsigned short* xbf    = (unsigned short*)(ws);             //  8 MB [2048][2048]
    unsigned short* wqkvT  = (unsigned short*)(ws + 8 * MB);    // 12 MB [3072][2048]
    unsigned short* woT    = (unsigned short*)(ws + 20 * MB);   //  8 MB [2048][2048]
    unsigned short* qbf    = (unsigned short*)(ws + 28 * MB);   //  8 MB [2048][2048]
    unsigned short* kbf    = (unsigned short*)(ws + 36 * MB);   //  2 MB [2048][512]
    unsigned short* vbf    = (unsigned short*)(ws + 38 * MB);   //  2 MB [2048][512]
    unsigned short* vbt    = (unsigned short*)(ws + 40 * MB);   //  2 MB [512][2048]
    unsigned short* attnbf = (unsigned short*)(ws);             //  8 MB (over xbf; xbf dead after QKV gemm)

    // 1. convert x + transpose weights (fused)
    prep<<<4096 + 2560, 256, 0, stream>>>(x, wq, wk, wv, wo, xbf, wqkvT, woT);

    // 2. fused QKV projection + RoPE epilogue -> qbf/kbf/vbf (768 blocks, 3/CU)
    gemm_qkv<<<dim3(QKV_N / 64, S_LEN / 128), 256, 0, stream>>>(xbf, wqkvT,
                                                                qbf, kbf, vbf, fcos, fsin);

    // 3. V transpose (with key permute) -> vbt
    transpose_v<<<dim3(KV_DIM / 64, S_LEN / 64), 256, 0, stream>>>(vbf, vbt);

    // 4. flash attention
    attn_mfma5<<<dim3(16, N_HEADS), 256, 0, stream>>>(qbf, kbf, vbt, attnbf);

    // 5. output projection (fp32 out, 512 blocks, 2/CU)
    gemm_bt64d<<<dim3(DIM / 64, S_LEN / 128), 256, 0, stream>>>(attnbf, woT, d_out,
                                                                S_LEN, DIM, DIM, 0);
}